// Round 1
// baseline (1206.985 us; speedup 1.0000x reference)
//
#include <hip/hip_runtime.h>

#define BM 128
#define BN 128
#define BK 16

// One 128x128 C-tile of C = A * B^T, A:[M,K] row-major, B:[N,K] row-major,
// C row-major with ldC = 512. K % 16 == 0. 256 threads, 8x8 micro-tile.
__device__ __forceinline__ void gemm_tile_128(
    const float* __restrict__ A, const float* __restrict__ B,
    float* __restrict__ C, int K, int m0, int n0)
{
    __shared__ float At[BK][BM];   // transposed: [k][m]
    __shared__ float Bt[BK][BN];   // transposed: [k][n]

    const int tid = threadIdx.x;        // 0..255
    const int tx = tid & 15;            // 0..15
    const int ty = tid >> 4;            // 0..15

    float acc[8][8];
#pragma unroll
    for (int i = 0; i < 8; ++i)
#pragma unroll
        for (int j = 0; j < 8; ++j) acc[i][j] = 0.0f;

    const int lrow = tid >> 1;          // 0..127 (tile row this thread stages)
    const int lkq  = (tid & 1) * 8;     // 0 or 8 (k-quad base)

    const float* Arow = A + (size_t)(m0 + lrow) * (size_t)K;
    const float* Brow = B + (size_t)(n0 + lrow) * (size_t)K;

    for (int k0 = 0; k0 < K; k0 += BK) {
#pragma unroll
        for (int j = 0; j < 2; ++j) {
            const int kq = lkq + j * 4;
            float4 va = *(const float4*)(Arow + k0 + kq);
            At[kq + 0][lrow] = va.x;
            At[kq + 1][lrow] = va.y;
            At[kq + 2][lrow] = va.z;
            At[kq + 3][lrow] = va.w;
            float4 vb = *(const float4*)(Brow + k0 + kq);
            Bt[kq + 0][lrow] = vb.x;
            Bt[kq + 1][lrow] = vb.y;
            Bt[kq + 2][lrow] = vb.z;
            Bt[kq + 3][lrow] = vb.w;
        }
        __syncthreads();

#pragma unroll
        for (int kk = 0; kk < BK; ++kk) {
            float4 a0 = *(const float4*)&At[kk][ty * 4];
            float4 a1 = *(const float4*)&At[kk][64 + ty * 4];
            float4 b0 = *(const float4*)&Bt[kk][tx * 4];
            float4 b1 = *(const float4*)&Bt[kk][64 + tx * 4];
            float a[8] = {a0.x, a0.y, a0.z, a0.w, a1.x, a1.y, a1.z, a1.w};
            float b[8] = {b0.x, b0.y, b0.z, b0.w, b1.x, b1.y, b1.z, b1.w};
#pragma unroll
            for (int i = 0; i < 8; ++i)
#pragma unroll
                for (int j = 0; j < 8; ++j)
                    acc[i][j] = fmaf(a[i], b[j], acc[i][j]);
        }
        __syncthreads();
    }

#pragma unroll
    for (int i = 0; i < 8; ++i) {
        const int rl = (i < 4) ? (ty * 4 + i) : (64 + ty * 4 + (i - 4));
        float* crow = C + (size_t)(m0 + rl) * 512 + n0;
        float4 v0 = make_float4(acc[i][0], acc[i][1], acc[i][2], acc[i][3]);
        float4 v1 = make_float4(acc[i][4], acc[i][5], acc[i][6], acc[i][7]);
        *(float4*)(crow + tx * 4)      = v0;
        *(float4*)(crow + 64 + tx * 4) = v1;
    }
}

// Fused: blocks [0,512): Apical = TE[16384,3136] @ Wa^T -> Abuf[16384,512]
//        blocks [512,528): Basal = SE[512,3136] @ Wb^T -> Cb[512,512]
__global__ __launch_bounds__(256) void k_front(
    const float* __restrict__ TE, const float* __restrict__ SE,
    const float* __restrict__ Wa, const float* __restrict__ Wb,
    float* __restrict__ Abuf, float* __restrict__ Cb)
{
    const int bid = blockIdx.x;
    if (bid < 512) {
        gemm_tile_128(TE, Wa, Abuf, 3136, (bid >> 2) * 128, (bid & 3) * 128);
    } else {
        const int b = bid - 512;
        gemm_tile_128(SE, Wb, Cb, 3136, (b >> 2) * 128, (b & 3) * 128);
    }
}

// H = SP[16384,512] @ W1^T[512,512] -> H[16384,512]
__global__ __launch_bounds__(256) void k_gemm3(
    const float* __restrict__ SP, const float* __restrict__ W1,
    float* __restrict__ H)
{
    const int bid = blockIdx.x;
    gemm_tile_128(SP, W1, H, 512, (bid >> 2) * 128, (bid & 3) * 128);
}

// mb/ma/ms scan over T=8; emits SP[t][r][f] in {0,1}.
// One thread per (r, f-quad): r in [0,2048), 128 quads per row.
__global__ __launch_bounds__(256) void k_scan1(
    const float* __restrict__ Abuf, const float* __restrict__ Cb,
    float* __restrict__ SP)
{
    const int idx = blockIdx.x * 256 + threadIdx.x;   // 262144 total
    const int r = idx >> 7;
    const int f = (idx & 127) << 2;
    const int b = r >> 5;

    float mb[4] = {0, 0, 0, 0}, ma[4] = {0, 0, 0, 0}, ms[4] = {0, 0, 0, 0};
#pragma unroll
    for (int t = 0; t < 8; ++t) {
        float4 av = *(const float4*)(Abuf + ((size_t)(t * 2048 + r) << 9) + f);
        float4 bv = *(const float4*)(Cb + ((size_t)(t * 64 + b) << 9) + f);
        float a[4] = {av.x, av.y, av.z, av.w};
        float ba[4] = {bv.x, bv.y, bv.z, bv.w};
        float sp[4];
#pragma unroll
        for (int c = 0; c < 4; ++c) {
            mb[c] = mb[c] + (ba[c] - mb[c]) * 0.5f;
            ma[c] = ma[c] + (a[c] - ma[c]) * 0.5f;
            ms[c] = ms[c] + (ma[c] + mb[c] - ms[c]) * 0.5f;
            sp[c] = (ms[c] > 1.0f) ? 1.0f : 0.0f;
            ms[c] = (ms[c] > 1.0f) ? 0.0f : ms[c];
        }
        *(float4*)(SP + ((size_t)(t * 2048 + r) << 9) + f) =
            make_float4(sp[0], sp[1], sp[2], sp[3]);
    }
}

// ml scan over T=8; emits spmean[r][f] = (1/8) sum_t sp2_t.
__global__ __launch_bounds__(256) void k_scan2(
    const float* __restrict__ H, const float* __restrict__ b1,
    float* __restrict__ spmean)
{
    const int idx = blockIdx.x * 256 + threadIdx.x;
    const int r = idx >> 7;
    const int f = (idx & 127) << 2;

    float4 b1v = *(const float4*)(b1 + f);
    float bb[4] = {b1v.x, b1v.y, b1v.z, b1v.w};
    float ml[4] = {0, 0, 0, 0}, acc[4] = {0, 0, 0, 0};
#pragma unroll
    for (int t = 0; t < 8; ++t) {
        float4 hv = *(const float4*)(H + ((size_t)(t * 2048 + r) << 9) + f);
        float h[4] = {hv.x, hv.y, hv.z, hv.w};
#pragma unroll
        for (int c = 0; c < 4; ++c) {
            float hb = h[c] + bb[c];
            ml[c] = ml[c] + (hb - ml[c]) * 0.5f;
            float s2 = (ml[c] > 0.5f) ? 1.0f : 0.0f;
            acc[c] += s2;
            ml[c] = (ml[c] > 0.5f) ? 0.0f : ml[c];
        }
    }
    *(float4*)(spmean + ((size_t)r << 9) + f) =
        make_float4(acc[0] * 0.125f, acc[1] * 0.125f, acc[2] * 0.125f, acc[3] * 0.125f);
}

// out[b,l,s] = spmean[row=b*32+s] . W2[l] + b2[l];  out is [64,18,32]
__global__ __launch_bounds__(64) void k_out(
    const float* __restrict__ spmean, const float* __restrict__ W2,
    const float* __restrict__ b2, float* __restrict__ out)
{
    __shared__ float row[512];
    const int r = blockIdx.x;          // 0..2047
    const int tid = threadIdx.x;       // 0..63

    const float4* src = (const float4*)(spmean + ((size_t)r << 9));
    ((float4*)row)[tid]      = src[tid];
    ((float4*)row)[tid + 64] = src[tid + 64];
    __syncthreads();

    if (tid < 18) {
        const float4* w = (const float4*)(W2 + (size_t)tid * 512);
        float acc = 0.0f;
#pragma unroll 4
        for (int c = 0; c < 128; ++c) {
            float4 wv = w[c];
            float4 rv = ((const float4*)row)[c];
            acc += rv.x * wv.x + rv.y * wv.y + rv.z * wv.z + rv.w * wv.w;
        }
        acc += b2[tid];
        const int b = r >> 5, s = r & 31;
        out[((size_t)(b * 18 + tid) << 5) + s] = acc;
    }
}

extern "C" void kernel_launch(void* const* d_in, const int* in_sizes, int n_in,
                              void* d_out, int out_size, void* d_ws, size_t ws_size,
                              hipStream_t stream)
{
    const float* SE = (const float*)d_in[0];  // [8,64,3136]
    const float* TE = (const float*)d_in[1];  // [8,2048,3136]
    const float* Wb = (const float*)d_in[2];  // [512,3136]
    const float* Wa = (const float*)d_in[3];  // [512,3136]
    const float* W1 = (const float*)d_in[4];  // [512,512]
    const float* b1 = (const float*)d_in[5];  // [512]
    const float* W2 = (const float*)d_in[6];  // [18,512]
    const float* b2 = (const float*)d_in[7];  // [18]
    float* out = (float*)d_out;               // [64,18,32]

    float* ws = (float*)d_ws;
    float* Abuf   = ws;                 // [16384,512] apical; reused as H
    float* SP     = ws + 8388608;       // [16384,512] spikes
    float* Cb     = ws + 16777216;      // [512,512] basal
    float* spmean = ws + 17039360;      // [2048,512]
    // total: 18,087,936 floats = 72.4 MB

    hipLaunchKernelGGL(k_front, dim3(528), dim3(256), 0, stream,
                       TE, SE, Wa, Wb, Abuf, Cb);
    hipLaunchKernelGGL(k_scan1, dim3(1024), dim3(256), 0, stream,
                       Abuf, Cb, SP);
    hipLaunchKernelGGL(k_gemm3, dim3(512), dim3(256), 0, stream,
                       SP, W1, Abuf);
    hipLaunchKernelGGL(k_scan2, dim3(1024), dim3(256), 0, stream,
                       Abuf, b1, spmean);
    hipLaunchKernelGGL(k_out, dim3(2048), dim3(64), 0, stream,
                       spmean, W2, b2, out);
}

// Round 2
// 672.639 us; speedup vs baseline: 1.7944x; 1.7944x over previous
//
#include <hip/hip_runtime.h>

typedef _Float16 f16x8 __attribute__((ext_vector_type(8)));
typedef _Float16 f16x4 __attribute__((ext_vector_type(4)));
typedef float    f32x4 __attribute__((ext_vector_type(4)));

#define SPLIT_SCALE 4096.0f
#define SPLIT_INV   (1.0f / 4096.0f)

// ---------------------------------------------------------------------------
// Split-precision f16 MFMA GEMM tile: C[128x128] = A[M,K] @ B[N,K]^T, fp32 io.
// A,B fp32 row-major; C fp32 row-major ldc=512. K % 32 == 0.
// 256 threads = 4 waves in 2x2; each wave computes 64x64 as 4x4 MFMA tiles.
// Numerics: a = ah + al/4096 (f16 each); 3 products, 2 accumulators.
// ---------------------------------------------------------------------------
__device__ __forceinline__ void gemm_f16split(
    const float* __restrict__ A, const float* __restrict__ B,
    float* __restrict__ C, int K, int m0, int n0)
{
    __shared__ _Float16 Ah[128][40];
    __shared__ _Float16 Al[128][40];
    __shared__ _Float16 Bh[128][40];
    __shared__ _Float16 Bl[128][40];

    const int tid  = threadIdx.x;
    const int lane = tid & 63;
    const int wave = tid >> 6;
    const int wm   = (wave >> 1) * 64;
    const int wn   = (wave & 1) * 64;
    const int quad = lane >> 4;
    const int l15  = lane & 15;

    f32x4 accm[4][4], accc[4][4];
#pragma unroll
    for (int i = 0; i < 4; ++i)
#pragma unroll
        for (int j = 0; j < 4; ++j) {
            accm[i][j] = (f32x4){0.f, 0.f, 0.f, 0.f};
            accc[i][j] = (f32x4){0.f, 0.f, 0.f, 0.f};
        }

    const int srow = tid >> 1;          // 0..127: tile row this thread stages
    const int skh  = (tid & 1) * 16;    // 0 or 16: k-offset within BK=32

    const float* Ap = A + (size_t)(m0 + srow) * (size_t)K + skh;
    const float* Bp = B + (size_t)(n0 + srow) * (size_t)K + skh;

    for (int k0 = 0; k0 < K; k0 += 32) {
        // ---- issue global loads early (latency overlaps barrier wait) ----
        float4 va0 = *(const float4*)(Ap + k0);
        float4 va1 = *(const float4*)(Ap + k0 + 4);
        float4 va2 = *(const float4*)(Ap + k0 + 8);
        float4 va3 = *(const float4*)(Ap + k0 + 12);
        float4 vb0 = *(const float4*)(Bp + k0);
        float4 vb1 = *(const float4*)(Bp + k0 + 4);
        float4 vb2 = *(const float4*)(Bp + k0 + 8);
        float4 vb3 = *(const float4*)(Bp + k0 + 12);

        __syncthreads();   // previous tile fully consumed

        // ---- convert fp32 -> f16 hi/lo and stage to LDS ----
        {
            float va[16] = {va0.x, va0.y, va0.z, va0.w, va1.x, va1.y, va1.z, va1.w,
                            va2.x, va2.y, va2.z, va2.w, va3.x, va3.y, va3.z, va3.w};
            float vb[16] = {vb0.x, vb0.y, vb0.z, vb0.w, vb1.x, vb1.y, vb1.z, vb1.w,
                            vb2.x, vb2.y, vb2.z, vb2.w, vb3.x, vb3.y, vb3.z, vb3.w};
            f16x8 ah0, ah1, al0, al1, bh0, bh1, bl0, bl1;
#pragma unroll
            for (int j = 0; j < 8; ++j) {
                float v = va[j];
                _Float16 h = (_Float16)v;
                ah0[j] = h;
                al0[j] = (_Float16)((v - (float)h) * SPLIT_SCALE);
                v = va[j + 8];
                h = (_Float16)v;
                ah1[j] = h;
                al1[j] = (_Float16)((v - (float)h) * SPLIT_SCALE);
                v = vb[j];
                h = (_Float16)v;
                bh0[j] = h;
                bl0[j] = (_Float16)((v - (float)h) * SPLIT_SCALE);
                v = vb[j + 8];
                h = (_Float16)v;
                bh1[j] = h;
                bl1[j] = (_Float16)((v - (float)h) * SPLIT_SCALE);
            }
            *(f16x8*)&Ah[srow][skh]     = ah0;
            *(f16x8*)&Ah[srow][skh + 8] = ah1;
            *(f16x8*)&Al[srow][skh]     = al0;
            *(f16x8*)&Al[srow][skh + 8] = al1;
            *(f16x8*)&Bh[srow][skh]     = bh0;
            *(f16x8*)&Bh[srow][skh + 8] = bh1;
            *(f16x8*)&Bl[srow][skh]     = bl0;
            *(f16x8*)&Bl[srow][skh + 8] = bl1;
        }
        __syncthreads();

        // ---- fragments: A[m=lane&15][k=quad*8+j], B^T via W rows same way ----
        f16x8 fah[4], fal[4], fbh[4], fbl[4];
#pragma unroll
        for (int i = 0; i < 4; ++i) {
            fah[i] = *(const f16x8*)&Ah[wm + i * 16 + l15][quad * 8];
            fal[i] = *(const f16x8*)&Al[wm + i * 16 + l15][quad * 8];
            fbh[i] = *(const f16x8*)&Bh[wn + i * 16 + l15][quad * 8];
            fbl[i] = *(const f16x8*)&Bl[wn + i * 16 + l15][quad * 8];
        }
#pragma unroll
        for (int i = 0; i < 4; ++i)
#pragma unroll
            for (int j = 0; j < 4; ++j) {
                accm[i][j] = __builtin_amdgcn_mfma_f32_16x16x32_f16(fah[i], fbh[j], accm[i][j], 0, 0, 0);
                accc[i][j] = __builtin_amdgcn_mfma_f32_16x16x32_f16(fah[i], fbl[j], accc[i][j], 0, 0, 0);
                accc[i][j] = __builtin_amdgcn_mfma_f32_16x16x32_f16(fal[i], fbh[j], accc[i][j], 0, 0, 0);
            }
    }

    // ---- epilogue: D[m=quad*4+reg][n=lane&15] ----
#pragma unroll
    for (int i = 0; i < 4; ++i)
#pragma unroll
        for (int j = 0; j < 4; ++j) {
#pragma unroll
            for (int r = 0; r < 4; ++r) {
                const int row = m0 + wm + i * 16 + quad * 4 + r;
                const int col = n0 + wn + j * 16 + l15;
                C[(size_t)row * 512 + col] = accm[i][j][r] + accc[i][j][r] * SPLIT_INV;
            }
        }
}

// blocks [0,512): Apical = TE[16384,3136] @ Wa^T ; [512,528): Basal = SE @ Wb^T
__global__ __launch_bounds__(256, 2) void k_front(
    const float* __restrict__ TE, const float* __restrict__ SE,
    const float* __restrict__ Wa, const float* __restrict__ Wb,
    float* __restrict__ Abuf, float* __restrict__ Cb)
{
    const int bid = blockIdx.x;
    if (bid < 512) {
        gemm_f16split(TE, Wa, Abuf, 3136, (bid >> 2) * 128, (bid & 3) * 128);
    } else {
        const int b = bid - 512;
        gemm_f16split(SE, Wb, Cb, 3136, (b >> 2) * 128, (b & 3) * 128);
    }
}

// W1 fp32 -> W1h + W1l/4096 (f16, lo pre-scaled)
__global__ __launch_bounds__(256) void k_prep(
    const float* __restrict__ W1, _Float16* __restrict__ W1h, _Float16* __restrict__ W1l)
{
    const int i4 = (blockIdx.x * 256 + threadIdx.x) * 4;
    float4 v = *(const float4*)(W1 + i4);
    float vv[4] = {v.x, v.y, v.z, v.w};
    f16x4 h, l;
#pragma unroll
    for (int j = 0; j < 4; ++j) {
        _Float16 hh = (_Float16)vv[j];
        h[j] = hh;
        l[j] = (_Float16)((vv[j] - (float)hh) * SPLIT_SCALE);
    }
    *(f16x4*)(W1h + i4) = h;
    *(f16x4*)(W1l + i4) = l;
}

// H = SP[16384,512](f16 exact) @ (W1h + W1l/4096)^T -> H fp32
__global__ __launch_bounds__(256, 2) void k_gemm3(
    const _Float16* __restrict__ SPh, const _Float16* __restrict__ W1h,
    const _Float16* __restrict__ W1l, float* __restrict__ H)
{
    __shared__ _Float16 As[128][40];
    __shared__ _Float16 Bhs[128][40];
    __shared__ _Float16 Bls[128][40];

    const int bid = blockIdx.x;
    const int m0 = (bid >> 2) * 128, n0 = (bid & 3) * 128;

    const int tid  = threadIdx.x;
    const int lane = tid & 63;
    const int wave = tid >> 6;
    const int wm   = (wave >> 1) * 64;
    const int wn   = (wave & 1) * 64;
    const int quad = lane >> 4;
    const int l15  = lane & 15;

    f32x4 accm[4][4], accl[4][4];
#pragma unroll
    for (int i = 0; i < 4; ++i)
#pragma unroll
        for (int j = 0; j < 4; ++j) {
            accm[i][j] = (f32x4){0.f, 0.f, 0.f, 0.f};
            accl[i][j] = (f32x4){0.f, 0.f, 0.f, 0.f};
        }

    const int srow = tid >> 1;
    const int skh  = (tid & 1) * 16;

    const _Float16* Ap  = SPh + (size_t)(m0 + srow) * 512 + skh;
    const _Float16* Bhp = W1h + (size_t)(n0 + srow) * 512 + skh;
    const _Float16* Blp = W1l + (size_t)(n0 + srow) * 512 + skh;

    for (int k0 = 0; k0 < 512; k0 += 32) {
        f16x8 a0  = *(const f16x8*)(Ap + k0);
        f16x8 a1  = *(const f16x8*)(Ap + k0 + 8);
        f16x8 bh0 = *(const f16x8*)(Bhp + k0);
        f16x8 bh1 = *(const f16x8*)(Bhp + k0 + 8);
        f16x8 bl0 = *(const f16x8*)(Blp + k0);
        f16x8 bl1 = *(const f16x8*)(Blp + k0 + 8);

        __syncthreads();
        *(f16x8*)&As[srow][skh]      = a0;
        *(f16x8*)&As[srow][skh + 8]  = a1;
        *(f16x8*)&Bhs[srow][skh]     = bh0;
        *(f16x8*)&Bhs[srow][skh + 8] = bh1;
        *(f16x8*)&Bls[srow][skh]     = bl0;
        *(f16x8*)&Bls[srow][skh + 8] = bl1;
        __syncthreads();

        f16x8 fa[4], fbh[4], fbl[4];
#pragma unroll
        for (int i = 0; i < 4; ++i) {
            fa[i]  = *(const f16x8*)&As[wm + i * 16 + l15][quad * 8];
            fbh[i] = *(const f16x8*)&Bhs[wn + i * 16 + l15][quad * 8];
            fbl[i] = *(const f16x8*)&Bls[wn + i * 16 + l15][quad * 8];
        }
#pragma unroll
        for (int i = 0; i < 4; ++i)
#pragma unroll
            for (int j = 0; j < 4; ++j) {
                accm[i][j] = __builtin_amdgcn_mfma_f32_16x16x32_f16(fa[i], fbh[j], accm[i][j], 0, 0, 0);
                accl[i][j] = __builtin_amdgcn_mfma_f32_16x16x32_f16(fa[i], fbl[j], accl[i][j], 0, 0, 0);
            }
    }

#pragma unroll
    for (int i = 0; i < 4; ++i)
#pragma unroll
        for (int j = 0; j < 4; ++j)
#pragma unroll
            for (int r = 0; r < 4; ++r) {
                const int row = m0 + wm + i * 16 + quad * 4 + r;
                const int col = n0 + wn + j * 16 + l15;
                H[(size_t)row * 512 + col] = accm[i][j][r] + accl[i][j][r] * SPLIT_INV;
            }
}

// mb/ma/ms scan over T=8; emits SP (f16, exact 0/1).
__global__ __launch_bounds__(256) void k_scan1(
    const float* __restrict__ Abuf, const float* __restrict__ Cb,
    _Float16* __restrict__ SPh)
{
    const int idx = blockIdx.x * 256 + threadIdx.x;   // 262144
    const int r = idx >> 7;
    const int f = (idx & 127) << 2;
    const int b = r >> 5;

    float mb[4] = {0, 0, 0, 0}, ma[4] = {0, 0, 0, 0}, ms[4] = {0, 0, 0, 0};
#pragma unroll
    for (int t = 0; t < 8; ++t) {
        float4 av = *(const float4*)(Abuf + ((size_t)(t * 2048 + r) << 9) + f);
        float4 bv = *(const float4*)(Cb + ((size_t)(t * 64 + b) << 9) + f);
        float a[4] = {av.x, av.y, av.z, av.w};
        float ba[4] = {bv.x, bv.y, bv.z, bv.w};
        f16x4 sp;
#pragma unroll
        for (int c = 0; c < 4; ++c) {
            mb[c] = mb[c] + (ba[c] - mb[c]) * 0.5f;
            ma[c] = ma[c] + (a[c] - ma[c]) * 0.5f;
            ms[c] = ms[c] + (ma[c] + mb[c] - ms[c]) * 0.5f;
            sp[c] = (ms[c] > 1.0f) ? (_Float16)1.0f : (_Float16)0.0f;
            ms[c] = (ms[c] > 1.0f) ? 0.0f : ms[c];
        }
        *(f16x4*)(SPh + ((size_t)(t * 2048 + r) << 9) + f) = sp;
    }
}

// ml scan over T=8; emits spmean = (1/8) sum_t sp2_t.
__global__ __launch_bounds__(256) void k_scan2(
    const float* __restrict__ H, const float* __restrict__ b1,
    float* __restrict__ spmean)
{
    const int idx = blockIdx.x * 256 + threadIdx.x;
    const int r = idx >> 7;
    const int f = (idx & 127) << 2;

    float4 b1v = *(const float4*)(b1 + f);
    float bb[4] = {b1v.x, b1v.y, b1v.z, b1v.w};
    float ml[4] = {0, 0, 0, 0}, acc[4] = {0, 0, 0, 0};
#pragma unroll
    for (int t = 0; t < 8; ++t) {
        float4 hv = *(const float4*)(H + ((size_t)(t * 2048 + r) << 9) + f);
        float h[4] = {hv.x, hv.y, hv.z, hv.w};
#pragma unroll
        for (int c = 0; c < 4; ++c) {
            float hb = h[c] + bb[c];
            ml[c] = ml[c] + (hb - ml[c]) * 0.5f;
            float s2 = (ml[c] > 0.5f) ? 1.0f : 0.0f;
            acc[c] += s2;
            ml[c] = (ml[c] > 0.5f) ? 0.0f : ml[c];
        }
    }
    *(float4*)(spmean + ((size_t)r << 9) + f) =
        make_float4(acc[0] * 0.125f, acc[1] * 0.125f, acc[2] * 0.125f, acc[3] * 0.125f);
}

// out[b,l,s] = spmean[row] . W2[l] + b2[l];  out is [64,18,32]
__global__ __launch_bounds__(64) void k_out(
    const float* __restrict__ spmean, const float* __restrict__ W2,
    const float* __restrict__ b2, float* __restrict__ out)
{
    __shared__ float row[512];
    const int r = blockIdx.x;
    const int tid = threadIdx.x;

    const float4* src = (const float4*)(spmean + ((size_t)r << 9));
    ((float4*)row)[tid]      = src[tid];
    ((float4*)row)[tid + 64] = src[tid + 64];
    __syncthreads();

    if (tid < 18) {
        const float4* w = (const float4*)(W2 + (size_t)tid * 512);
        float acc = 0.0f;
#pragma unroll 4
        for (int c = 0; c < 128; ++c) {
            float4 wv = w[c];
            float4 rv = ((const float4*)row)[c];
            acc += rv.x * wv.x + rv.y * wv.y + rv.z * wv.z + rv.w * wv.w;
        }
        acc += b2[tid];
        const int b = r >> 5, s = r & 31;
        out[((size_t)(b * 18 + tid) << 5) + s] = acc;
    }
}

extern "C" void kernel_launch(void* const* d_in, const int* in_sizes, int n_in,
                              void* d_out, int out_size, void* d_ws, size_t ws_size,
                              hipStream_t stream)
{
    const float* SE = (const float*)d_in[0];
    const float* TE = (const float*)d_in[1];
    const float* Wb = (const float*)d_in[2];
    const float* Wa = (const float*)d_in[3];
    const float* W1 = (const float*)d_in[4];
    const float* b1 = (const float*)d_in[5];
    const float* W2 = (const float*)d_in[6];
    const float* b2 = (const float*)d_in[7];
    float* out = (float*)d_out;

    char* ws = (char*)d_ws;
    float*    Abuf   = (float*)(ws);                    // 16384*512*4 = 33,554,432
    float*    Cb     = (float*)(ws + 33554432);         // 512*512*4   =  1,048,576
    float*    spmean = (float*)(ws + 34603008);         // 2048*512*4  =  4,194,304
    _Float16* SPh    = (_Float16*)(ws + 38797312);      // 16384*512*2 = 16,777,216
    _Float16* W1h    = (_Float16*)(ws + 55574528);      // 512*512*2   =    524,288
    _Float16* W1l    = (_Float16*)(ws + 56098816);      // 512*512*2   =    524,288
    // total 56,623,104 bytes

    hipLaunchKernelGGL(k_prep, dim3(256), dim3(256), 0, stream, W1, W1h, W1l);
    hipLaunchKernelGGL(k_front, dim3(528), dim3(256), 0, stream,
                       TE, SE, Wa, Wb, Abuf, Cb);
    hipLaunchKernelGGL(k_scan1, dim3(1024), dim3(256), 0, stream, Abuf, Cb, SPh);
    hipLaunchKernelGGL(k_gemm3, dim3(512), dim3(256), 0, stream, SPh, W1h, W1l, Abuf);
    hipLaunchKernelGGL(k_scan2, dim3(1024), dim3(256), 0, stream, Abuf, b1, spmean);
    hipLaunchKernelGGL(k_out, dim3(2048), dim3(64), 0, stream, spmean, W2, b2, out);
}

// Round 3
// 671.908 us; speedup vs baseline: 1.7964x; 1.0011x over previous
//
#include <hip/hip_runtime.h>

typedef _Float16 f16x8 __attribute__((ext_vector_type(8)));
typedef _Float16 f16x4 __attribute__((ext_vector_type(4)));
typedef float    f32x4 __attribute__((ext_vector_type(4)));

#define SPLIT_SCALE 4096.0f
#define SPLIT_INV   (1.0f / 4096.0f)

// async global->LDS DMA, 16 bytes per lane. LDS dest = wave-uniform base +
// lane*16 (HW-defined); global src is per-lane.
__device__ __forceinline__ void gld_lds16(const void* g, void* l) {
    __builtin_amdgcn_global_load_lds(
        (const __attribute__((address_space(1))) unsigned int*)g,
        (__attribute__((address_space(3))) unsigned int*)l,
        16, 0, 0);
}

// fp32 -> (hi f16, lo f16 prescaled by 4096). 8 elements/thread.
__global__ __launch_bounds__(256) void k_cvt(
    const float* __restrict__ src, _Float16* __restrict__ h, _Float16* __restrict__ l)
{
    const size_t i = ((size_t)blockIdx.x * 256 + threadIdx.x) * 8;
    float4 v0 = *(const float4*)(src + i);
    float4 v1 = *(const float4*)(src + i + 4);
    float vv[8] = {v0.x, v0.y, v0.z, v0.w, v1.x, v1.y, v1.z, v1.w};
    f16x8 hh, ll;
#pragma unroll
    for (int j = 0; j < 8; ++j) {
        _Float16 x = (_Float16)vv[j];
        hh[j] = x;
        ll[j] = (_Float16)((vv[j] - (float)x) * SPLIT_SCALE);
    }
    *(f16x8*)(h + i) = hh;
    *(f16x8*)(l + i) = ll;
}

// ---------------------------------------------------------------------------
// m97-style split GEMM: C[128x128] = (Ah+Al/4096)[M,K] @ (Bh+Bl/4096)[N,K]^T
// K % 32 == 0. 256 thr = 4 waves (2x2 of 64x64). LDS tiles [128][32] f16,
// unpadded (global_load_lds lane order), 2-barrier K-loop.
// ---------------------------------------------------------------------------
__device__ __forceinline__ void gemm_split_core(
    const _Float16* __restrict__ Asrc_h, const _Float16* __restrict__ Asrc_l,
    const _Float16* __restrict__ Bsrc_h, const _Float16* __restrict__ Bsrc_l,
    float* __restrict__ C, int K, int m0, int n0)
{
    __shared__ _Float16 Ah[128 * 32];
    __shared__ _Float16 Al[128 * 32];
    __shared__ _Float16 Bh[128 * 32];
    __shared__ _Float16 Bl[128 * 32];

    const int tid  = threadIdx.x;
    const int lane = tid & 63;
    const int wave = tid >> 6;
    const int wm   = (wave >> 1) * 64;
    const int wn   = (wave & 1) * 64;
    const int quad = lane >> 4;
    const int l15  = lane & 15;

    // staging: wave w covers rows [w*32, w*32+32), 2 DMA instr per tile
    const int r0 = wave * 32 + (lane >> 2);       // rows for j=0 (j=1: +16)
    const int kc = (lane & 3) * 8;                // k col (f16 elems)
    const size_t gA0 = (size_t)(m0 + r0) * (size_t)K + kc;
    const size_t gA1 = gA0 + (size_t)16 * K;
    const size_t gB0 = (size_t)(n0 + r0) * (size_t)K + kc;
    const size_t gB1 = gB0 + (size_t)16 * K;
    const int l0 = (wave * 32) * 32;              // LDS elem offset, j=0
    const int l1 = l0 + 16 * 32;

    f32x4 accm[4][4], accc[4][4];
#pragma unroll
    for (int i = 0; i < 4; ++i)
#pragma unroll
        for (int j = 0; j < 4; ++j) {
            accm[i][j] = (f32x4){0.f, 0.f, 0.f, 0.f};
            accc[i][j] = (f32x4){0.f, 0.f, 0.f, 0.f};
        }

    for (int k0 = 0; k0 < K; k0 += 32) {
        __syncthreads();                          // prev tile fully consumed
        gld_lds16(Asrc_h + gA0 + k0, Ah + l0);
        gld_lds16(Asrc_h + gA1 + k0, Ah + l1);
        gld_lds16(Asrc_l + gA0 + k0, Al + l0);
        gld_lds16(Asrc_l + gA1 + k0, Al + l1);
        gld_lds16(Bsrc_h + gB0 + k0, Bh + l0);
        gld_lds16(Bsrc_h + gB1 + k0, Bh + l1);
        gld_lds16(Bsrc_l + gB0 + k0, Bl + l0);
        gld_lds16(Bsrc_l + gB1 + k0, Bl + l1);
        __syncthreads();                          // DMA landed (vmcnt drain)

        f16x8 fah[4], fal[4], fbh[4], fbl[4];
#pragma unroll
        for (int i = 0; i < 4; ++i) {
            fah[i] = *(const f16x8*)&Ah[(wm + i * 16 + l15) * 32 + quad * 8];
            fal[i] = *(const f16x8*)&Al[(wm + i * 16 + l15) * 32 + quad * 8];
            fbh[i] = *(const f16x8*)&Bh[(wn + i * 16 + l15) * 32 + quad * 8];
            fbl[i] = *(const f16x8*)&Bl[(wn + i * 16 + l15) * 32 + quad * 8];
        }
#pragma unroll
        for (int i = 0; i < 4; ++i)
#pragma unroll
            for (int j = 0; j < 4; ++j) {
                accm[i][j] = __builtin_amdgcn_mfma_f32_16x16x32_f16(fah[i], fbh[j], accm[i][j], 0, 0, 0);
                accc[i][j] = __builtin_amdgcn_mfma_f32_16x16x32_f16(fah[i], fbl[j], accc[i][j], 0, 0, 0);
                accc[i][j] = __builtin_amdgcn_mfma_f32_16x16x32_f16(fal[i], fbh[j], accc[i][j], 0, 0, 0);
            }
    }

    // D[m = quad*4 + r][n = lane&15]
#pragma unroll
    for (int i = 0; i < 4; ++i)
#pragma unroll
        for (int j = 0; j < 4; ++j)
#pragma unroll
            for (int r = 0; r < 4; ++r) {
                const int row = m0 + wm + i * 16 + quad * 4 + r;
                const int col = n0 + wn + j * 16 + l15;
                C[(size_t)row * 512 + col] = accm[i][j][r] + accc[i][j][r] * SPLIT_INV;
            }
}

// blocks [0,512): Apical = TE @ Wa^T ; [512,528): Basal = SE @ Wb^T
__global__ __launch_bounds__(256, 2) void k_front(
    const _Float16* __restrict__ TEh, const _Float16* __restrict__ TEl,
    const _Float16* __restrict__ SEh, const _Float16* __restrict__ SEl,
    const _Float16* __restrict__ Wah, const _Float16* __restrict__ Wal,
    const _Float16* __restrict__ Wbh, const _Float16* __restrict__ Wbl,
    float* __restrict__ Abuf, float* __restrict__ Cb)
{
    const int bid = blockIdx.x;
    if (bid < 512) {
        gemm_split_core(TEh, TEl, Wah, Wal, Abuf, 3136, (bid >> 2) * 128, (bid & 3) * 128);
    } else {
        const int b = bid - 512;
        gemm_split_core(SEh, SEl, Wbh, Wbl, Cb, 3136, (b >> 2) * 128, (b & 3) * 128);
    }
}

// H = SP(f16 exact) @ (W1h + W1l/4096)^T ; same structure, A needs no split.
__global__ __launch_bounds__(256, 2) void k_gemm3(
    const _Float16* __restrict__ SPh, const _Float16* __restrict__ W1h,
    const _Float16* __restrict__ W1l, float* __restrict__ H)
{
    __shared__ _Float16 As[128 * 32];
    __shared__ _Float16 Bhs[128 * 32];
    __shared__ _Float16 Bls[128 * 32];

    const int bid = blockIdx.x;
    const int m0 = (bid >> 2) * 128, n0 = (bid & 3) * 128;
    const int tid  = threadIdx.x;
    const int lane = tid & 63;
    const int wave = tid >> 6;
    const int wm   = (wave >> 1) * 64;
    const int wn   = (wave & 1) * 64;
    const int quad = lane >> 4;
    const int l15  = lane & 15;

    const int r0 = wave * 32 + (lane >> 2);
    const int kc = (lane & 3) * 8;
    const size_t gA0 = (size_t)(m0 + r0) * 512 + kc;
    const size_t gA1 = gA0 + (size_t)16 * 512;
    const size_t gB0 = (size_t)(n0 + r0) * 512 + kc;
    const size_t gB1 = gB0 + (size_t)16 * 512;
    const int l0 = (wave * 32) * 32;
    const int l1 = l0 + 16 * 32;

    f32x4 accm[4][4], accl[4][4];
#pragma unroll
    for (int i = 0; i < 4; ++i)
#pragma unroll
        for (int j = 0; j < 4; ++j) {
            accm[i][j] = (f32x4){0.f, 0.f, 0.f, 0.f};
            accl[i][j] = (f32x4){0.f, 0.f, 0.f, 0.f};
        }

    for (int k0 = 0; k0 < 512; k0 += 32) {
        __syncthreads();
        gld_lds16(SPh + gA0 + k0, As + l0);
        gld_lds16(SPh + gA1 + k0, As + l1);
        gld_lds16(W1h + gB0 + k0, Bhs + l0);
        gld_lds16(W1h + gB1 + k0, Bhs + l1);
        gld_lds16(W1l + gB0 + k0, Bls + l0);
        gld_lds16(W1l + gB1 + k0, Bls + l1);
        __syncthreads();

        f16x8 fa[4], fbh[4], fbl[4];
#pragma unroll
        for (int i = 0; i < 4; ++i) {
            fa[i]  = *(const f16x8*)&As[(wm + i * 16 + l15) * 32 + quad * 8];
            fbh[i] = *(const f16x8*)&Bhs[(wn + i * 16 + l15) * 32 + quad * 8];
            fbl[i] = *(const f16x8*)&Bls[(wn + i * 16 + l15) * 32 + quad * 8];
        }
#pragma unroll
        for (int i = 0; i < 4; ++i)
#pragma unroll
            for (int j = 0; j < 4; ++j) {
                accm[i][j] = __builtin_amdgcn_mfma_f32_16x16x32_f16(fa[i], fbh[j], accm[i][j], 0, 0, 0);
                accl[i][j] = __builtin_amdgcn_mfma_f32_16x16x32_f16(fa[i], fbl[j], accl[i][j], 0, 0, 0);
            }
    }

#pragma unroll
    for (int i = 0; i < 4; ++i)
#pragma unroll
        for (int j = 0; j < 4; ++j)
#pragma unroll
            for (int r = 0; r < 4; ++r) {
                const int row = m0 + wm + i * 16 + quad * 4 + r;
                const int col = n0 + wn + j * 16 + l15;
                H[(size_t)row * 512 + col] = accm[i][j][r] + accl[i][j][r] * SPLIT_INV;
            }
}

// mb/ma/ms scan over T=8; emits SP (f16, exact 0/1).
__global__ __launch_bounds__(256) void k_scan1(
    const float* __restrict__ Abuf, const float* __restrict__ Cb,
    _Float16* __restrict__ SPh)
{
    const int idx = blockIdx.x * 256 + threadIdx.x;
    const int r = idx >> 7;
    const int f = (idx & 127) << 2;
    const int b = r >> 5;

    float mb[4] = {0, 0, 0, 0}, ma[4] = {0, 0, 0, 0}, ms[4] = {0, 0, 0, 0};
#pragma unroll
    for (int t = 0; t < 8; ++t) {
        float4 av = *(const float4*)(Abuf + ((size_t)(t * 2048 + r) << 9) + f);
        float4 bv = *(const float4*)(Cb + ((size_t)(t * 64 + b) << 9) + f);
        float a[4] = {av.x, av.y, av.z, av.w};
        float ba[4] = {bv.x, bv.y, bv.z, bv.w};
        f16x4 sp;
#pragma unroll
        for (int c = 0; c < 4; ++c) {
            mb[c] = mb[c] + (ba[c] - mb[c]) * 0.5f;
            ma[c] = ma[c] + (a[c] - ma[c]) * 0.5f;
            ms[c] = ms[c] + (ma[c] + mb[c] - ms[c]) * 0.5f;
            sp[c] = (ms[c] > 1.0f) ? (_Float16)1.0f : (_Float16)0.0f;
            ms[c] = (ms[c] > 1.0f) ? 0.0f : ms[c];
        }
        *(f16x4*)(SPh + ((size_t)(t * 2048 + r) << 9) + f) = sp;
    }
}

// ml scan over T=8; emits spmean = (1/8) sum_t sp2_t.
__global__ __launch_bounds__(256) void k_scan2(
    const float* __restrict__ H, const float* __restrict__ b1,
    float* __restrict__ spmean)
{
    const int idx = blockIdx.x * 256 + threadIdx.x;
    const int r = idx >> 7;
    const int f = (idx & 127) << 2;

    float4 b1v = *(const float4*)(b1 + f);
    float bb[4] = {b1v.x, b1v.y, b1v.z, b1v.w};
    float ml[4] = {0, 0, 0, 0}, acc[4] = {0, 0, 0, 0};
#pragma unroll
    for (int t = 0; t < 8; ++t) {
        float4 hv = *(const float4*)(H + ((size_t)(t * 2048 + r) << 9) + f);
        float h[4] = {hv.x, hv.y, hv.z, hv.w};
#pragma unroll
        for (int c = 0; c < 4; ++c) {
            float hb = h[c] + bb[c];
            ml[c] = ml[c] + (hb - ml[c]) * 0.5f;
            float s2 = (ml[c] > 0.5f) ? 1.0f : 0.0f;
            acc[c] += s2;
            ml[c] = (ml[c] > 0.5f) ? 0.0f : ml[c];
        }
    }
    *(float4*)(spmean + ((size_t)r << 9) + f) =
        make_float4(acc[0] * 0.125f, acc[1] * 0.125f, acc[2] * 0.125f, acc[3] * 0.125f);
}

// out[b,l,s] = spmean[row] . W2[l] + b2[l];  out is [64,18,32]
__global__ __launch_bounds__(64) void k_out(
    const float* __restrict__ spmean, const float* __restrict__ W2,
    const float* __restrict__ b2, float* __restrict__ out)
{
    __shared__ float row[512];
    const int r = blockIdx.x;
    const int tid = threadIdx.x;

    const float4* src = (const float4*)(spmean + ((size_t)r << 9));
    ((float4*)row)[tid]      = src[tid];
    ((float4*)row)[tid + 64] = src[tid + 64];
    __syncthreads();

    if (tid < 18) {
        const float4* w = (const float4*)(W2 + (size_t)tid * 512);
        float acc = 0.0f;
#pragma unroll 4
        for (int c = 0; c < 128; ++c) {
            float4 wv = w[c];
            float4 rv = ((const float4*)row)[c];
            acc += rv.x * wv.x + rv.y * wv.y + rv.z * wv.z + rv.w * wv.w;
        }
        acc += b2[tid];
        const int b = r >> 5, s = r & 31;
        out[((size_t)(b * 18 + tid) << 5) + s] = acc;
    }
}

extern "C" void kernel_launch(void* const* d_in, const int* in_sizes, int n_in,
                              void* d_out, int out_size, void* d_ws, size_t ws_size,
                              hipStream_t stream)
{
    const float* SE = (const float*)d_in[0];   // [8,64,3136]
    const float* TE = (const float*)d_in[1];   // [8,2048,3136]
    const float* Wb = (const float*)d_in[2];   // [512,3136]
    const float* Wa = (const float*)d_in[3];   // [512,3136]
    const float* W1 = (const float*)d_in[4];   // [512,512]
    const float* b1 = (const float*)d_in[5];   // [512]
    const float* W2 = (const float*)d_in[6];   // [18,512]
    const float* b2 = (const float*)d_in[7];   // [18]
    float* out = (float*)d_out;                // [64,18,32]

    char* ws = (char*)d_ws;
    size_t off = 0;
    float*    Abuf   = (float*)(ws + off);     off += 33554432;  // [16384,512] f32 (apical, then H)
    float*    Cb     = (float*)(ws + off);     off += 1048576;   // [512,512] f32
    float*    spmean = (float*)(ws + off);     off += 4194304;   // [2048,512] f32
    _Float16* SPh    = (_Float16*)(ws + off);  off += 16777216;  // [16384,512] f16
    _Float16* W1h    = (_Float16*)(ws + off);  off += 524288;
    _Float16* W1l    = (_Float16*)(ws + off);  off += 524288;
    _Float16* SEh    = (_Float16*)(ws + off);  off += 3211264;
    _Float16* SEl    = (_Float16*)(ws + off);  off += 3211264;
    _Float16* Wah    = (_Float16*)(ws + off);  off += 3211264;
    _Float16* Wal    = (_Float16*)(ws + off);  off += 3211264;
    _Float16* Wbh    = (_Float16*)(ws + off);  off += 3211264;
    _Float16* Wbl    = (_Float16*)(ws + off);  off += 3211264;
    _Float16* TEh    = (_Float16*)(ws + off);  off += 102760448;
    _Float16* TEl    = (_Float16*)(ws + off);  off += 102760448;
    // total: 281,411,584 bytes (~268.4 MiB)

    // convert all operands to f16 hi/lo pairs (bandwidth-bound)
    hipLaunchKernelGGL(k_cvt, dim3(25088), dim3(256), 0, stream, TE, TEh, TEl);
    hipLaunchKernelGGL(k_cvt, dim3(784),   dim3(256), 0, stream, SE, SEh, SEl);
    hipLaunchKernelGGL(k_cvt, dim3(784),   dim3(256), 0, stream, Wa, Wah, Wal);
    hipLaunchKernelGGL(k_cvt, dim3(784),   dim3(256), 0, stream, Wb, Wbh, Wbl);
    hipLaunchKernelGGL(k_cvt, dim3(128),   dim3(256), 0, stream, W1, W1h, W1l);

    hipLaunchKernelGGL(k_front, dim3(528), dim3(256), 0, stream,
                       TEh, TEl, SEh, SEl, Wah, Wal, Wbh, Wbl, Abuf, Cb);
    hipLaunchKernelGGL(k_scan1, dim3(1024), dim3(256), 0, stream, Abuf, Cb, SPh);
    hipLaunchKernelGGL(k_gemm3, dim3(512), dim3(256), 0, stream, SPh, W1h, W1l, Abuf);
    hipLaunchKernelGGL(k_scan2, dim3(1024), dim3(256), 0, stream, Abuf, b1, spmean);
    hipLaunchKernelGGL(k_out, dim3(2048), dim3(64), 0, stream, spmean, W2, b2, out);
}